// Round 16
// baseline (189.102 us; speedup 1.0000x reference)
//
#include <hip/hip_runtime.h>

typedef unsigned int uint32;
typedef __bf16 bf16x8 __attribute__((ext_vector_type(8)));
typedef float f32x4 __attribute__((ext_vector_type(4)));

typedef __attribute__((address_space(1))) unsigned int as1_uint;
typedef __attribute__((address_space(3))) unsigned int as3_uint;

// ---------- constants ----------
#define BATCH 4096
#define D0D1 2048
#define MM 1600
#define NCHUNKS 20
#define RANK 15
#define CSIZE 80
#define TDIM 1200   // SIZE*RANK
#define NOUT 3000

// stage-2 packed weight layout v2 (XOR swizzle, bias folded at k=80):
#define SL_KF 2560          // elems per kf block (80*32)
#define SL_TEN 7680         // elems per tensor (3 kf)
#define SL_DATA 15360       // data elems per slice
#define SLICE_EL 16384      // padded elems per slice
#define SLICE_B 32768       // padded bytes per slice

__device__ __forceinline__ unsigned short f2bf(float f) {
  unsigned int u = __builtin_bit_cast(unsigned int, f);
  u = (u + 0x7fffu + ((u >> 16) & 1u)) >> 16;
  return (unsigned short)u;
}

__device__ __forceinline__ void gload_lds16(const void* g, void* lds) {
  __builtin_amdgcn_global_load_lds((as1_uint*)g, (as3_uint*)lds, 16, 0, 0);
}

template <int N>
__device__ __forceinline__ void wait_vmcnt() {
  asm volatile("s_waitcnt vmcnt(%0)" :: "n"(N) : "memory");
}
__device__ __forceinline__ void barrier_mem() {
  asm volatile("s_barrier" ::: "memory");
}

// ---------- fused cast f32 -> bf16 for all 5 tensors (1 launch) ----------
#define CV_X0 1048576
#define CV_X1 2097152
#define CV_W0 2506752
#define CV_W1 2916352
#define CV_WO 3516352
__global__ __launch_bounds__(256) void cast_all_k(
    const float* __restrict__ x0, const float* __restrict__ x1,
    const float* __restrict__ W0, const float* __restrict__ W1,
    const float* __restrict__ Wout,
    unsigned short* __restrict__ xb0, unsigned short* __restrict__ xb1,
    unsigned short* __restrict__ Wb0, unsigned short* __restrict__ Wb1,
    unsigned short* __restrict__ Woutb) {
  int v = blockIdx.x * 256 + threadIdx.x;
  if (v >= CV_WO) return;
  const float* s;
  unsigned short* d;
  int off;
  if (v < CV_X0)      { s = x0;   d = xb0;   off = v; }
  else if (v < CV_X1) { s = x1;   d = xb1;   off = v - CV_X0; }
  else if (v < CV_W0) { s = W0;   d = Wb0;   off = v - CV_X1; }
  else if (v < CV_W1) { s = W1;   d = Wb1;   off = v - CV_W0; }
  else                { s = Wout; d = Woutb; off = v - CV_W1; }
  size_t i = (size_t)off * 8;
  float4 v0 = *(const float4*)(s + i);
  float4 v1 = *(const float4*)(s + i + 4);
  uint4 o;
  o.x = (uint32)f2bf(v0.x) | ((uint32)f2bf(v0.y) << 16);
  o.y = (uint32)f2bf(v0.z) | ((uint32)f2bf(v0.w) << 16);
  o.z = (uint32)f2bf(v1.x) | ((uint32)f2bf(v1.y) << 16);
  o.w = (uint32)f2bf(v1.z) | ((uint32)f2bf(v1.w) << 16);
  *(uint4*)(d + i) = o;
}

// ---------- pack mW + mb into swizzled, bias-folded, padded layout v2 ----------
__global__ __launch_bounds__(256) void cast_mwp_k(
    const float* __restrict__ mW0, const float* __restrict__ mb0,
    const float* __restrict__ mW1, const float* __restrict__ mb1,
    unsigned short* __restrict__ mWP) {
  const int c = blockIdx.z, r = blockIdx.y;
  int chunk = blockIdx.x * 256 + threadIdx.x;   // 0..2047
  int el = chunk * 8;
  unsigned short out[8];
  if (el >= SL_DATA) {
#pragma unroll
    for (int e = 0; e < 8; ++e) out[e] = 0;
  } else {
    int tensor = el / SL_TEN;
    int rem = el - tensor * SL_TEN;
    int kf = rem / SL_KF;
    int rem2 = rem - kf * SL_KF;
    int t = rem2 >> 5;                 // 0..79
    int gp = (rem2 & 31) >> 3;         // position granule
    int g = gp ^ ((t >> 1) & 3);       // logical k-granule
    int k0 = kf * 32 + g * 8;
    const float* Wt = (tensor ? mW1 : mW0) +
                      ((size_t)c * TDIM + (size_t)r * CSIZE + t) * CSIZE;
    float bias = (tensor ? mb1 : mb0)[(size_t)c * TDIM + (size_t)r * CSIZE + t];
#pragma unroll
    for (int e = 0; e < 8; ++e) {
      int k = k0 + e;
      float val = (k < CSIZE) ? Wt[k] : (k == CSIZE ? bias : 0.f);
      out[e] = f2bf(val);
    }
  }
  uint4 o;
  o.x = (uint32)out[0] | ((uint32)out[1] << 16);
  o.y = (uint32)out[2] | ((uint32)out[3] << 16);
  o.z = (uint32)out[4] | ((uint32)out[5] << 16);
  o.w = (uint32)out[6] | ((uint32)out[7] << 16);
  *(uint4*)(mWP + ((size_t)(c * RANK + r)) * SLICE_EL + el) = o;
}

// ---------- NT GEMM core v6.3: v6.2 + T5 setprio around MFMA clusters ----------
// 8 waves (2M x 4N), BK=64, dbuf, 1 {vmcnt(0); s_barrier} per K-tile, both STGs
// issued under two MFMA clusters; odd waves consume ks1 before ks0 (offset-table
// folded permutation -> wave role diversity, the T5 prerequisite).
// Granule swizzle kg ^= (row&7) (measured conflict-free).
template <bool BF16OUT>
__device__ __forceinline__ void gemm256_core(const unsigned short* __restrict__ A,
                                             const unsigned short* __restrict__ B,
                                             const float* __restrict__ bias,
                                             void* __restrict__ Cv,
                                             char* lds, int N, int K, int nt,
                                             int bm0, int bn0) {
  const int tid = threadIdx.x;
  const int wave = tid >> 6, lane = tid & 63;
  const int wm = wave >> 2, wn = wave & 3;
  const int lrow = lane & 15, lj = lane >> 4;
  const int p = wave & 1;   // parity: phase order of ks

  uint32 eA[4], eB[4];
#pragma unroll
  for (int q = 0; q < 4; ++q) {
    int g = q * 512 + tid;                 // granule 0..2047 within 32KB half
    int r = g >> 3;                        // row 0..255
    int kg = (g & 7) ^ (r & 7);            // inverse swizzle on the source side
    eA[q] = (uint32)((bm0 + r) * K + kg * 8) * 2;
    int rb = bn0 + r;
    if (rb > N - 1) rb = N - 1;            // clamp keeps ragged-N loads in-bounds
    eB[q] = (uint32)(rb * K + kg * 8) * 2;
  }
  int offA[2][8], offB[2][4];
#pragma unroll
  for (int m = 0; m < 8; ++m) {
    int row = wm * 128 + m * 16 + lrow;
#pragma unroll
    for (int ph = 0; ph < 2; ++ph) {
      int ks = ph ^ p;
      offA[ph][m] = (row * 8 + ((ks * 4 + lj) ^ (row & 7))) * 16;
    }
  }
#pragma unroll
  for (int n = 0; n < 4; ++n) {
    int row = wn * 64 + n * 16 + lrow;
#pragma unroll
    for (int ph = 0; ph < 2; ++ph) {
      int ks = ph ^ p;
      offB[ph][n] = 32768 + (row * 8 + ((ks * 4 + lj) ^ (row & 7))) * 16;
    }
  }

  f32x4 acc[8][4];
#pragma unroll
  for (int m = 0; m < 8; ++m)
#pragma unroll
    for (int n = 0; n < 4; ++n) acc[m][n] = 0.f;

  const char* Ab = (const char*)A;
  const char* Bb = (const char*)B;
  auto STGA = [&](int t, int buf) {
    char* base = lds + buf * 65536;
    uint32 kb = (uint32)t * 128;
#pragma unroll
    for (int q = 0; q < 4; ++q)
      gload_lds16(Ab + eA[q] + kb, base + (q * 512 + tid) * 16);
  };
  auto STGB = [&](int t, int buf) {
    char* base = lds + buf * 65536 + 32768;
    uint32 kb = (uint32)t * 128;
#pragma unroll
    for (int q = 0; q < 4; ++q)
      gload_lds16(Bb + eB[q] + kb, base + (q * 512 + tid) * 16);
  };

  STGA(0, 0);
  STGB(0, 0);
  wait_vmcnt<0>();
  barrier_mem();

  for (int t = 0; t < nt; ++t) {
    const int buf = t & 1;
    const char* base = lds + buf * 65536;
    bf16x8 av[8], bv[4];

    // ---- phase 0 (physical ks = p) ----
#pragma unroll
    for (int n = 0; n < 4; ++n) bv[n] = *(const bf16x8*)(base + offB[0][n]);
#pragma unroll
    for (int m = 0; m < 8; ++m) av[m] = *(const bf16x8*)(base + offA[0][m]);
    if (t < nt - 1) {
      STGA(t + 1, buf ^ 1);
      STGB(t + 1, buf ^ 1);   // both here: drain covered by 2 MFMA clusters
    }
    __builtin_amdgcn_s_setprio(1);
#pragma unroll
    for (int m = 0; m < 8; ++m)
#pragma unroll
      for (int n = 0; n < 4; ++n)
        acc[m][n] = __builtin_amdgcn_mfma_f32_16x16x32_bf16(av[m], bv[n], acc[m][n], 0, 0, 0);
    __builtin_amdgcn_s_setprio(0);

    // ---- phase 1 (physical ks = p^1) ----
#pragma unroll
    for (int n = 0; n < 4; ++n) bv[n] = *(const bf16x8*)(base + offB[1][n]);
#pragma unroll
    for (int m = 0; m < 8; ++m) av[m] = *(const bf16x8*)(base + offA[1][m]);
    __builtin_amdgcn_s_setprio(1);
#pragma unroll
    for (int m = 0; m < 8; ++m)
#pragma unroll
      for (int n = 0; n < 4; ++n)
        acc[m][n] = __builtin_amdgcn_mfma_f32_16x16x32_bf16(av[m], bv[n], acc[m][n], 0, 0, 0);
    __builtin_amdgcn_s_setprio(0);

    if (t < nt - 1) {
      wait_vmcnt<0>();     // next tile fully landed
      barrier_mem();       // single barrier per K-tile
    }
  }

  // epilogue: C/D layout col=lane&15, row=(lane>>4)*4+j
#pragma unroll
  for (int n = 0; n < 4; ++n) {
    int col = bn0 + wn * 64 + n * 16 + lrow;
    if (col < N) {
      float bv2 = bias[col];
#pragma unroll
      for (int m = 0; m < 8; ++m) {
#pragma unroll
        for (int j = 0; j < 4; ++j) {
          int row = bm0 + wm * 128 + m * 16 + lj * 4 + j;
          float v = acc[m][n][j] + bv2;
          if (BF16OUT)
            ((unsigned short*)Cv)[(size_t)row * N + col] = f2bf(v);
          else
            ((float*)Cv)[(size_t)row * N + col] = v;
        }
      }
    }
  }
}

// stage-1 dual GEMM: grid 224 = 7(N) x 16(M) x 2(tensor), XCD-chunked (224%8==0)
__global__ __launch_bounds__(512, 2) void gemm_dual_256(
    const unsigned short* A0, const unsigned short* B0, const float* bias0, unsigned short* C0,
    const unsigned short* A1, const unsigned short* B1, const float* bias1, unsigned short* C1) {
  __shared__ char lds[131072];
  int wg = (blockIdx.x & 7) * 28 + (blockIdx.x >> 3);   // contiguous chunk per XCD
  int bz = wg >= 112;
  wg -= bz * 112;
  int by = wg / 7, bx = wg % 7;
  const unsigned short* A = bz ? A1 : A0;
  const unsigned short* B = bz ? B1 : B0;
  const float* bias = bz ? bias1 : bias0;
  unsigned short* C = bz ? C1 : C0;
  gemm256_core<true>(A, B, bias, C, lds, MM, D0D1, D0D1 / 64, by * 256, bx * 256);
}

// ---------- stage-3 GEMM v7.1: 256(M) x 192(N), grid 256 (all CUs) + setprio ----------
__global__ __launch_bounds__(512, 2) void gemm_out_192(
    const unsigned short* __restrict__ A, const unsigned short* __restrict__ B,
    const float* __restrict__ bias, float* __restrict__ C) {
  __shared__ char lds[114688];
  const int N = NOUT, K = MM, nt = MM / 64;
  int wg = (blockIdx.x & 7) * 32 + (blockIdx.x >> 3);   // XCD-chunked, 256%8==0
  int by = wg / 16, bx = wg % 16;
  const int bm0 = by * 256, bn0 = bx * 192;

  const int tid = threadIdx.x;
  const int wave = tid >> 6, lane = tid & 63;
  const int wm = wave >> 1, wn = wave & 1;
  const int lrow = lane & 15, lj = lane >> 4;
  const int p = wave & 1;   // parity stagger

  uint32 eA[4], eB[3];
#pragma unroll
  for (int q = 0; q < 4; ++q) {
    int g = q * 512 + tid;                 // 0..2047
    int r = g >> 3;
    int kg = (g & 7) ^ (r & 7);
    eA[q] = (uint32)((bm0 + r) * K + kg * 8) * 2;
  }
#pragma unroll
  for (int q = 0; q < 3; ++q) {
    int g = q * 512 + tid;                 // 0..1535
    int r = g >> 3;                        // row 0..191
    int kg = (g & 7) ^ (r & 7);
    int rb = bn0 + r;
    if (rb > N - 1) rb = N - 1;            // clamp keeps ragged-N loads in-bounds
    eB[q] = (uint32)(rb * K + kg * 8) * 2;
  }
  int offA[2][4], offB[2][6];
#pragma unroll
  for (int m = 0; m < 4; ++m) {
    int row = wm * 64 + m * 16 + lrow;
#pragma unroll
    for (int ph = 0; ph < 2; ++ph) {
      int ks = ph ^ p;
      offA[ph][m] = (row * 8 + ((ks * 4 + lj) ^ (row & 7))) * 16;
    }
  }
#pragma unroll
  for (int n = 0; n < 6; ++n) {
    int row = wn * 96 + n * 16 + lrow;
#pragma unroll
    for (int ph = 0; ph < 2; ++ph) {
      int ks = ph ^ p;
      offB[ph][n] = 32768 + (row * 8 + ((ks * 4 + lj) ^ (row & 7))) * 16;
    }
  }

  f32x4 acc[4][6];
#pragma unroll
  for (int m = 0; m < 4; ++m)
#pragma unroll
    for (int n = 0; n < 6; ++n) acc[m][n] = 0.f;

  const char* Ab = (const char*)A;
  const char* Bb = (const char*)B;
  auto STGA = [&](int t, int buf) {
    char* base = lds + buf * 57344;
    uint32 kb = (uint32)t * 128;
#pragma unroll
    for (int q = 0; q < 4; ++q)
      gload_lds16(Ab + eA[q] + kb, base + (q * 512 + tid) * 16);
  };
  auto STGB = [&](int t, int buf) {
    char* base = lds + buf * 57344 + 32768;
    uint32 kb = (uint32)t * 128;
#pragma unroll
    for (int q = 0; q < 3; ++q)
      gload_lds16(Bb + eB[q] + kb, base + (q * 512 + tid) * 16);
  };

  STGA(0, 0);
  STGB(0, 0);
  wait_vmcnt<0>();
  barrier_mem();

  for (int t = 0; t < nt; ++t) {
    const int buf = t & 1;
    const char* base = lds + buf * 57344;
    bf16x8 av[4], bv[6];

    // ---- phase 0 (physical ks = p) ----
#pragma unroll
    for (int n = 0; n < 6; ++n) bv[n] = *(const bf16x8*)(base + offB[0][n]);
#pragma unroll
    for (int m = 0; m < 4; ++m) av[m] = *(const bf16x8*)(base + offA[0][m]);
    if (t < nt - 1) {
      STGA(t + 1, buf ^ 1);
      STGB(t + 1, buf ^ 1);
    }
    __builtin_amdgcn_s_setprio(1);
#pragma unroll
    for (int m = 0; m < 4; ++m)
#pragma unroll
      for (int n = 0; n < 6; ++n)
        acc[m][n] = __builtin_amdgcn_mfma_f32_16x16x32_bf16(av[m], bv[n], acc[m][n], 0, 0, 0);
    __builtin_amdgcn_s_setprio(0);

    // ---- phase 1 (physical ks = p^1) ----
#pragma unroll
    for (int n = 0; n < 6; ++n) bv[n] = *(const bf16x8*)(base + offB[1][n]);
#pragma unroll
    for (int m = 0; m < 4; ++m) av[m] = *(const bf16x8*)(base + offA[1][m]);
    __builtin_amdgcn_s_setprio(1);
#pragma unroll
    for (int m = 0; m < 4; ++m)
#pragma unroll
      for (int n = 0; n < 6; ++n)
        acc[m][n] = __builtin_amdgcn_mfma_f32_16x16x32_bf16(av[m], bv[n], acc[m][n], 0, 0, 0);
    __builtin_amdgcn_s_setprio(0);

    if (t < nt - 1) {
      wait_vmcnt<0>();
      barrier_mem();
    }
  }

  // epilogue
#pragma unroll
  for (int n = 0; n < 6; ++n) {
    int col = bn0 + wn * 96 + n * 16 + lrow;
    if (col < N) {
      float bv2 = bias[col];
#pragma unroll
      for (int m = 0; m < 4; ++m) {
#pragma unroll
        for (int j = 0; j < 4; ++j) {
          int row = bm0 + wm * 64 + m * 16 + lj * 4 + j;
          C[(size_t)row * N + col] = acc[m][n][j] + bv2;
        }
      }
    }
  }
}

// ---------- stage 2 v3.3: chunk_fuse3 (round-11 form) + setprio on MFMA block ----------
__global__ __launch_bounds__(256, 2) void chunk_fuse3(
    const unsigned short* __restrict__ hb0, const unsigned short* __restrict__ hb1,
    const unsigned short* __restrict__ mWP, unsigned short* __restrict__ zb) {
  const int c = blockIdx.x, bt = blockIdx.y;
  __shared__ char wl[2][SLICE_B];   // 64 KB
  const int tid = threadIdx.x, wave = tid >> 6, lane = tid & 63;
  const int lrow = lane & 15, lj = lane >> 4;
  const int p = wave & 1;   // parity: kf iteration order (0,1,2) vs (2,1,0)

  bf16x8 bzero;
  bzero = (__bf16)0.0f;
  bf16x8 bone = bzero;
  bone[0] = (__bf16)1.0f;

  // h fragments -> registers in PERMUTED kf order; k=80 column = 1.0 (bias trick)
  bf16x8 a0[2][3], a1[2][3];
#pragma unroll
  for (int m = 0; m < 2; ++m)
#pragma unroll
    for (int i = 0; i < 3; ++i) {
      int kf = p ? 2 - i : i;
      int col = kf * 32 + lj * 8;
      int row = bt * 128 + wave * 32 + m * 16 + lrow;
      bf16x8 v0, v1;
      if (col < CSIZE) {
        size_t base = (size_t)row * MM + c * CSIZE + col;
        v0 = *(const bf16x8*)(hb0 + base);
        v1 = *(const bf16x8*)(hb1 + base);
      } else if (col == CSIZE) {
        v0 = bone; v1 = bone;
      } else {
        v0 = bzero; v1 = bzero;
      }
      a0[m][i] = v0;
      a1[m][i] = v1;
    }

  // swizzled W read offsets in the same permuted kf order
  int woff[3][5];
  const int key = (lrow >> 1) & 3;
#pragma unroll
  for (int i = 0; i < 3; ++i) {
    int kf = p ? 2 - i : i;
#pragma unroll
    for (int n = 0; n < 5; ++n) {
      int t = n * 16 + lrow;
      woff[i][n] = kf * (SL_KF * 2) + (t * 4 + (lj ^ key)) * 16;
    }
  }

  const char* wsrc = (const char*)(mWP) + (size_t)(c * RANK) * SLICE_B;
  auto STAGE = [&](int buf, int r) {
    const char* src = wsrc + (size_t)r * SLICE_B;
    char* dst = wl[buf];
#pragma unroll
    for (int k = 0; k < 8; ++k) {
      int i = k * 256 + tid;
      gload_lds16(src + (size_t)i * 16, dst + (size_t)i * 16);
    }
  };

  f32x4 zacc[2][5];
#pragma unroll
  for (int m = 0; m < 2; ++m)
#pragma unroll
    for (int n = 0; n < 5; ++n) zacc[m][n] = 0.f;
  f32x4 zero4 = 0.f;

  STAGE(0, 0);
  for (int r = 0; r < RANK; ++r) {
    int cur = r & 1;
    if (r < RANK - 1) {
      STAGE(cur ^ 1, r + 1);
      wait_vmcnt<8>();      // current slice landed; next 8 loads in flight
    } else {
      wait_vmcnt<0>();
    }
    __builtin_amdgcn_s_barrier();

    const char* wb = wl[cur];
    f32x4 y0[2][5], y1[2][5];
    __builtin_amdgcn_s_setprio(1);
#pragma unroll
    for (int i = 0; i < 3; ++i) {
#pragma unroll
      for (int n = 0; n < 5; ++n) {
        bf16x8 b0 = *(const bf16x8*)(wb + woff[i][n]);
        bf16x8 b1 = *(const bf16x8*)(wb + SL_TEN * 2 + woff[i][n]);
        if (i == 0) {
#pragma unroll
          for (int m = 0; m < 2; ++m) {
            y0[m][n] = __builtin_amdgcn_mfma_f32_16x16x32_bf16(a0[m][0], b0, zero4, 0, 0, 0);
            y1[m][n] = __builtin_amdgcn_mfma_f32_16x16x32_bf16(a1[m][0], b1, zero4, 0, 0, 0);
          }
        } else {
#pragma unroll
          for (int m = 0; m < 2; ++m) {
            y0[m][n] = __builtin_amdgcn_mfma_f32_16x16x32_bf16(a0[m][i], b0, y0[m][n], 0, 0, 0);
            y1[m][n] = __builtin_amdgcn_mfma_f32_16x16x32_bf16(a1[m][i], b1, y1[m][n], 0, 0, 0);
          }
        }
      }
    }
    __builtin_amdgcn_s_setprio(0);
    // bilinear accumulate (bias already inside y via k=80 column)
#pragma unroll
    for (int m = 0; m < 2; ++m)
#pragma unroll
      for (int n = 0; n < 5; ++n)
#pragma unroll
        for (int j = 0; j < 4; ++j)
          zacc[m][n][j] += y0[m][n][j] * y1[m][n][j];

    __builtin_amdgcn_s_barrier();  // all waves done reading wl[cur] before restage
  }

  // signed sqrt + per-row L2 norm over the 80 chunk cols, write bf16
#pragma unroll
  for (int m = 0; m < 2; ++m) {
    float g[5][4];
    float ssj[4] = {0.f, 0.f, 0.f, 0.f};
#pragma unroll
    for (int n = 0; n < 5; ++n)
#pragma unroll
      for (int j = 0; j < 4; ++j) {
        float v = zacc[m][n][j];
        float a = sqrtf(fabsf(v));
        float gv = v < 0.f ? -a : a;
        g[n][j] = gv;
        ssj[j] += gv * gv;
      }
#pragma unroll
    for (int j = 0; j < 4; ++j) {
      float s = ssj[j];
      s += __shfl_xor(s, 1);
      s += __shfl_xor(s, 2);
      s += __shfl_xor(s, 4);
      s += __shfl_xor(s, 8);
      float nrm = sqrtf(s);
      nrm = nrm > 1e-12f ? nrm : 1e-12f;
      ssj[j] = 1.f / nrm;
    }
#pragma unroll
    for (int n = 0; n < 5; ++n) {
      int scol = n * 16 + lrow;
#pragma unroll
      for (int j = 0; j < 4; ++j) {
        int row = bt * 128 + wave * 32 + m * 16 + lj * 4 + j;
        zb[(size_t)row * MM + c * CSIZE + scol] = f2bf(g[n][j] * ssj[j]);
      }
    }
  }
}

// ---------- workspace layout (bytes) ----------
#define OFF_XB0   ((size_t)0)
#define OFF_XB1   (OFF_XB0 + (size_t)BATCH * D0D1 * 2)
#define OFF_WB0   (OFF_XB1 + (size_t)BATCH * D0D1 * 2)
#define OFF_WB1   (OFF_WB0 + (size_t)MM * D0D1 * 2)
#define OFF_WOUTB (OFF_WB1 + (size_t)MM * D0D1 * 2)
#define OFF_HB0   (OFF_WOUTB + (size_t)NOUT * MM * 2)
#define OFF_HB1   (OFF_HB0 + (size_t)BATCH * MM * 2)
#define OFF_ZB    (OFF_HB1 + (size_t)BATCH * MM * 2)
#define WS_NEED   (OFF_ZB + (size_t)BATCH * MM * 2)
#define OFF_MWP   OFF_XB0   // mWP (9.8MB) aliases xb0 (16.8MB), packed after gemm_dual

extern "C" void kernel_launch(void* const* d_in, const int* in_sizes, int n_in,
                              void* d_out, int out_size, void* d_ws, size_t ws_size,
                              hipStream_t stream) {
  const float* x0   = (const float*)d_in[0];
  const float* x1   = (const float*)d_in[1];
  const float* W0   = (const float*)d_in[2];
  const float* b0   = (const float*)d_in[3];
  const float* W1   = (const float*)d_in[4];
  const float* b1   = (const float*)d_in[5];
  const float* mW0  = (const float*)d_in[6];
  const float* mb0  = (const float*)d_in[7];
  const float* mW1  = (const float*)d_in[8];
  const float* mb1  = (const float*)d_in[9];
  const float* Wout = (const float*)d_in[10];
  const float* bout = (const float*)d_in[11];

  if (ws_size < WS_NEED) return;

  char* ws = (char*)d_ws;
  unsigned short* xb0   = (unsigned short*)(ws + OFF_XB0);
  unsigned short* xb1   = (unsigned short*)(ws + OFF_XB1);
  unsigned short* Wb0   = (unsigned short*)(ws + OFF_WB0);
  unsigned short* Wb1   = (unsigned short*)(ws + OFF_WB1);
  unsigned short* Woutb = (unsigned short*)(ws + OFF_WOUTB);
  unsigned short* hb0   = (unsigned short*)(ws + OFF_HB0);
  unsigned short* hb1   = (unsigned short*)(ws + OFF_HB1);
  unsigned short* zb    = (unsigned short*)(ws + OFF_ZB);
  unsigned short* mWP   = (unsigned short*)(ws + OFF_MWP);

  // all 5 f32->bf16 casts in one launch
  hipLaunchKernelGGL(cast_all_k, dim3((CV_WO + 255) / 256), dim3(256), 0, stream,
                     x0, x1, W0, W1, Wout, xb0, xb1, Wb0, Wb1, Woutb);

  // stage 1: h0,h1 = x@W^T + b  -> bf16 [4096][1600]
  hipLaunchKernelGGL(gemm_dual_256, dim3(224), dim3(512), 0, stream,
                     xb0, Wb0, b0, hb0, xb1, Wb1, b1, hb1);

  // pack mW+mb (into xb0's space, now free): 300 slices x 2048 chunks
  hipLaunchKernelGGL(cast_mwp_k, dim3(8, RANK, NCHUNKS), dim3(256), 0, stream,
                     mW0, mb0, mW1, mb1, mWP);

  // stage 2: chunk MM + bilinear + signed sqrt + L2 norm -> zb bf16
  hipLaunchKernelGGL(chunk_fuse3, dim3(NCHUNKS, BATCH / 128), dim3(256), 0, stream,
                     hb0, hb1, mWP, zb);

  // stage 3: out = zn@Wout^T + bout -> f32 [4096][3000]
  hipLaunchKernelGGL(gemm_out_192, dim3(256), dim3(512), 0, stream,
                     zb, Woutb, bout, (float*)d_out);
}

// Round 17
// 186.171 us; speedup vs baseline: 1.0157x; 1.0157x over previous
//
#include <hip/hip_runtime.h>

typedef unsigned int uint32;
typedef __bf16 bf16x8 __attribute__((ext_vector_type(8)));
typedef float f32x4 __attribute__((ext_vector_type(4)));

typedef __attribute__((address_space(1))) unsigned int as1_uint;
typedef __attribute__((address_space(3))) unsigned int as3_uint;

// ---------- constants ----------
#define BATCH 4096
#define D0D1 2048
#define MM 1600
#define NCHUNKS 20
#define RANK 15
#define CSIZE 80
#define TDIM 1200   // SIZE*RANK
#define NOUT 3000

// stage-2 packed weight layout v2 (XOR swizzle, bias folded at k=80):
#define SL_KF 2560          // elems per kf block (80*32)
#define SL_TEN 7680         // elems per tensor (3 kf)
#define SL_DATA 15360       // data elems per slice
#define SLICE_EL 16384      // padded elems per slice
#define SLICE_B 32768       // padded bytes per slice

__device__ __forceinline__ unsigned short f2bf(float f) {
  unsigned int u = __builtin_bit_cast(unsigned int, f);
  u = (u + 0x7fffu + ((u >> 16) & 1u)) >> 16;
  return (unsigned short)u;
}

__device__ __forceinline__ void gload_lds16(const void* g, void* lds) {
  __builtin_amdgcn_global_load_lds((as1_uint*)g, (as3_uint*)lds, 16, 0, 0);
}

template <int N>
__device__ __forceinline__ void wait_vmcnt() {
  asm volatile("s_waitcnt vmcnt(%0)" :: "n"(N) : "memory");
}
__device__ __forceinline__ void barrier_mem() {
  asm volatile("s_barrier" ::: "memory");
}

// ---------- fused cast f32 -> bf16 for all 5 tensors (1 launch) ----------
#define CV_X0 1048576
#define CV_X1 2097152
#define CV_W0 2506752
#define CV_W1 2916352
#define CV_WO 3516352
__global__ __launch_bounds__(256) void cast_all_k(
    const float* __restrict__ x0, const float* __restrict__ x1,
    const float* __restrict__ W0, const float* __restrict__ W1,
    const float* __restrict__ Wout,
    unsigned short* __restrict__ xb0, unsigned short* __restrict__ xb1,
    unsigned short* __restrict__ Wb0, unsigned short* __restrict__ Wb1,
    unsigned short* __restrict__ Woutb) {
  int v = blockIdx.x * 256 + threadIdx.x;
  if (v >= CV_WO) return;
  const float* s;
  unsigned short* d;
  int off;
  if (v < CV_X0)      { s = x0;   d = xb0;   off = v; }
  else if (v < CV_X1) { s = x1;   d = xb1;   off = v - CV_X0; }
  else if (v < CV_W0) { s = W0;   d = Wb0;   off = v - CV_X1; }
  else if (v < CV_W1) { s = W1;   d = Wb1;   off = v - CV_W0; }
  else                { s = Wout; d = Woutb; off = v - CV_W1; }
  size_t i = (size_t)off * 8;
  float4 v0 = *(const float4*)(s + i);
  float4 v1 = *(const float4*)(s + i + 4);
  uint4 o;
  o.x = (uint32)f2bf(v0.x) | ((uint32)f2bf(v0.y) << 16);
  o.y = (uint32)f2bf(v0.z) | ((uint32)f2bf(v0.w) << 16);
  o.z = (uint32)f2bf(v1.x) | ((uint32)f2bf(v1.y) << 16);
  o.w = (uint32)f2bf(v1.z) | ((uint32)f2bf(v1.w) << 16);
  *(uint4*)(d + i) = o;
}

// ---------- pack mW + mb into swizzled, bias-folded, padded layout v2 ----------
__global__ __launch_bounds__(256) void cast_mwp_k(
    const float* __restrict__ mW0, const float* __restrict__ mb0,
    const float* __restrict__ mW1, const float* __restrict__ mb1,
    unsigned short* __restrict__ mWP) {
  const int c = blockIdx.z, r = blockIdx.y;
  int chunk = blockIdx.x * 256 + threadIdx.x;   // 0..2047
  int el = chunk * 8;
  unsigned short out[8];
  if (el >= SL_DATA) {
#pragma unroll
    for (int e = 0; e < 8; ++e) out[e] = 0;
  } else {
    int tensor = el / SL_TEN;
    int rem = el - tensor * SL_TEN;
    int kf = rem / SL_KF;
    int rem2 = rem - kf * SL_KF;
    int t = rem2 >> 5;                 // 0..79
    int gp = (rem2 & 31) >> 3;         // position granule
    int g = gp ^ ((t >> 1) & 3);       // logical k-granule
    int k0 = kf * 32 + g * 8;
    const float* Wt = (tensor ? mW1 : mW0) +
                      ((size_t)c * TDIM + (size_t)r * CSIZE + t) * CSIZE;
    float bias = (tensor ? mb1 : mb0)[(size_t)c * TDIM + (size_t)r * CSIZE + t];
#pragma unroll
    for (int e = 0; e < 8; ++e) {
      int k = k0 + e;
      float val = (k < CSIZE) ? Wt[k] : (k == CSIZE ? bias : 0.f);
      out[e] = f2bf(val);
    }
  }
  uint4 o;
  o.x = (uint32)out[0] | ((uint32)out[1] << 16);
  o.y = (uint32)out[2] | ((uint32)out[3] << 16);
  o.z = (uint32)out[4] | ((uint32)out[5] << 16);
  o.w = (uint32)out[6] | ((uint32)out[7] << 16);
  *(uint4*)(mWP + ((size_t)(c * RANK + r)) * SLICE_EL + el) = o;
}

// ---------- NT GEMM core v6.2 (measured best: 61.5us stage-1) ----------
// 8 waves (2M x 4N), BK=64, dbuf, 1 {vmcnt(0); s_barrier} per K-tile, both STGs
// issued under two MFMA clusters; odd waves consume ks1 before ks0 (offset-table
// folded permutation). Granule swizzle kg ^= (row&7) (measured conflict-free).
template <bool BF16OUT>
__device__ __forceinline__ void gemm256_core(const unsigned short* __restrict__ A,
                                             const unsigned short* __restrict__ B,
                                             const float* __restrict__ bias,
                                             void* __restrict__ Cv,
                                             char* lds, int N, int K, int nt,
                                             int bm0, int bn0) {
  const int tid = threadIdx.x;
  const int wave = tid >> 6, lane = tid & 63;
  const int wm = wave >> 2, wn = wave & 3;
  const int lrow = lane & 15, lj = lane >> 4;
  const int p = wave & 1;   // parity: phase order of ks

  uint32 eA[4], eB[4];
#pragma unroll
  for (int q = 0; q < 4; ++q) {
    int g = q * 512 + tid;                 // granule 0..2047 within 32KB half
    int r = g >> 3;                        // row 0..255
    int kg = (g & 7) ^ (r & 7);            // inverse swizzle on the source side
    eA[q] = (uint32)((bm0 + r) * K + kg * 8) * 2;
    int rb = bn0 + r;
    if (rb > N - 1) rb = N - 1;            // clamp keeps ragged-N loads in-bounds
    eB[q] = (uint32)(rb * K + kg * 8) * 2;
  }
  int offA[2][8], offB[2][4];
#pragma unroll
  for (int m = 0; m < 8; ++m) {
    int row = wm * 128 + m * 16 + lrow;
#pragma unroll
    for (int ph = 0; ph < 2; ++ph) {
      int ks = ph ^ p;
      offA[ph][m] = (row * 8 + ((ks * 4 + lj) ^ (row & 7))) * 16;
    }
  }
#pragma unroll
  for (int n = 0; n < 4; ++n) {
    int row = wn * 64 + n * 16 + lrow;
#pragma unroll
    for (int ph = 0; ph < 2; ++ph) {
      int ks = ph ^ p;
      offB[ph][n] = 32768 + (row * 8 + ((ks * 4 + lj) ^ (row & 7))) * 16;
    }
  }

  f32x4 acc[8][4];
#pragma unroll
  for (int m = 0; m < 8; ++m)
#pragma unroll
    for (int n = 0; n < 4; ++n) acc[m][n] = 0.f;

  const char* Ab = (const char*)A;
  const char* Bb = (const char*)B;
  auto STGA = [&](int t, int buf) {
    char* base = lds + buf * 65536;
    uint32 kb = (uint32)t * 128;
#pragma unroll
    for (int q = 0; q < 4; ++q)
      gload_lds16(Ab + eA[q] + kb, base + (q * 512 + tid) * 16);
  };
  auto STGB = [&](int t, int buf) {
    char* base = lds + buf * 65536 + 32768;
    uint32 kb = (uint32)t * 128;
#pragma unroll
    for (int q = 0; q < 4; ++q)
      gload_lds16(Bb + eB[q] + kb, base + (q * 512 + tid) * 16);
  };

  STGA(0, 0);
  STGB(0, 0);
  wait_vmcnt<0>();
  barrier_mem();

  for (int t = 0; t < nt; ++t) {
    const int buf = t & 1;
    const char* base = lds + buf * 65536;
    bf16x8 av[8], bv[4];

    // ---- phase 0 (physical ks = p) ----
#pragma unroll
    for (int n = 0; n < 4; ++n) bv[n] = *(const bf16x8*)(base + offB[0][n]);
#pragma unroll
    for (int m = 0; m < 8; ++m) av[m] = *(const bf16x8*)(base + offA[0][m]);
    if (t < nt - 1) {
      STGA(t + 1, buf ^ 1);
      STGB(t + 1, buf ^ 1);   // both here: drain covered by 2 MFMA clusters
    }
#pragma unroll
    for (int m = 0; m < 8; ++m)
#pragma unroll
      for (int n = 0; n < 4; ++n)
        acc[m][n] = __builtin_amdgcn_mfma_f32_16x16x32_bf16(av[m], bv[n], acc[m][n], 0, 0, 0);

    // ---- phase 1 (physical ks = p^1) ----
#pragma unroll
    for (int n = 0; n < 4; ++n) bv[n] = *(const bf16x8*)(base + offB[1][n]);
#pragma unroll
    for (int m = 0; m < 8; ++m) av[m] = *(const bf16x8*)(base + offA[1][m]);
#pragma unroll
    for (int m = 0; m < 8; ++m)
#pragma unroll
      for (int n = 0; n < 4; ++n)
        acc[m][n] = __builtin_amdgcn_mfma_f32_16x16x32_bf16(av[m], bv[n], acc[m][n], 0, 0, 0);

    if (t < nt - 1) {
      wait_vmcnt<0>();     // next tile fully landed
      barrier_mem();       // single barrier per K-tile
    }
  }

  // epilogue: C/D layout col=lane&15, row=(lane>>4)*4+j
#pragma unroll
  for (int n = 0; n < 4; ++n) {
    int col = bn0 + wn * 64 + n * 16 + lrow;
    if (col < N) {
      float bv2 = bias[col];
#pragma unroll
      for (int m = 0; m < 8; ++m) {
#pragma unroll
        for (int j = 0; j < 4; ++j) {
          int row = bm0 + wm * 128 + m * 16 + lj * 4 + j;
          float v = acc[m][n][j] + bv2;
          if (BF16OUT)
            ((unsigned short*)Cv)[(size_t)row * N + col] = f2bf(v);
          else
            ((float*)Cv)[(size_t)row * N + col] = v;
        }
      }
    }
  }
}

// stage-1 dual GEMM: grid 224 = 7(N) x 16(M) x 2(tensor), XCD-chunked (224%8==0)
__global__ __launch_bounds__(512, 2) void gemm_dual_256(
    const unsigned short* A0, const unsigned short* B0, const float* bias0, unsigned short* C0,
    const unsigned short* A1, const unsigned short* B1, const float* bias1, unsigned short* C1) {
  __shared__ char lds[131072];
  int wg = (blockIdx.x & 7) * 28 + (blockIdx.x >> 3);   // contiguous chunk per XCD
  int bz = wg >= 112;
  wg -= bz * 112;
  int by = wg / 7, bx = wg % 7;
  const unsigned short* A = bz ? A1 : A0;
  const unsigned short* B = bz ? B1 : B0;
  const float* bias = bz ? bias1 : bias0;
  unsigned short* C = bz ? C1 : C0;
  gemm256_core<true>(A, B, bias, C, lds, MM, D0D1, D0D1 / 64, by * 256, bx * 256);
}

// ---------- stage-3 GEMM v7: 256(M) x 192(N) tile -> grid 256 = ALL CUs busy ----------
__global__ __launch_bounds__(512, 2) void gemm_out_192(
    const unsigned short* __restrict__ A, const unsigned short* __restrict__ B,
    const float* __restrict__ bias, float* __restrict__ C) {
  __shared__ char lds[114688];
  const int N = NOUT, K = MM, nt = MM / 64;
  int wg = (blockIdx.x & 7) * 32 + (blockIdx.x >> 3);   // XCD-chunked, 256%8==0
  int by = wg / 16, bx = wg % 16;
  const int bm0 = by * 256, bn0 = bx * 192;

  const int tid = threadIdx.x;
  const int wave = tid >> 6, lane = tid & 63;
  const int wm = wave >> 1, wn = wave & 1;
  const int lrow = lane & 15, lj = lane >> 4;
  const int p = wave & 1;   // parity stagger

  uint32 eA[4], eB[3];
#pragma unroll
  for (int q = 0; q < 4; ++q) {
    int g = q * 512 + tid;                 // 0..2047
    int r = g >> 3;
    int kg = (g & 7) ^ (r & 7);
    eA[q] = (uint32)((bm0 + r) * K + kg * 8) * 2;
  }
#pragma unroll
  for (int q = 0; q < 3; ++q) {
    int g = q * 512 + tid;                 // 0..1535
    int r = g >> 3;                        // row 0..191
    int kg = (g & 7) ^ (r & 7);
    int rb = bn0 + r;
    if (rb > N - 1) rb = N - 1;            // clamp keeps ragged-N loads in-bounds
    eB[q] = (uint32)(rb * K + kg * 8) * 2;
  }
  int offA[2][4], offB[2][6];
#pragma unroll
  for (int m = 0; m < 4; ++m) {
    int row = wm * 64 + m * 16 + lrow;
#pragma unroll
    for (int ph = 0; ph < 2; ++ph) {
      int ks = ph ^ p;
      offA[ph][m] = (row * 8 + ((ks * 4 + lj) ^ (row & 7))) * 16;
    }
  }
#pragma unroll
  for (int n = 0; n < 6; ++n) {
    int row = wn * 96 + n * 16 + lrow;
#pragma unroll
    for (int ph = 0; ph < 2; ++ph) {
      int ks = ph ^ p;
      offB[ph][n] = 32768 + (row * 8 + ((ks * 4 + lj) ^ (row & 7))) * 16;
    }
  }

  f32x4 acc[4][6];
#pragma unroll
  for (int m = 0; m < 4; ++m)
#pragma unroll
    for (int n = 0; n < 6; ++n) acc[m][n] = 0.f;

  const char* Ab = (const char*)A;
  const char* Bb = (const char*)B;
  auto STGA = [&](int t, int buf) {
    char* base = lds + buf * 57344;
    uint32 kb = (uint32)t * 128;
#pragma unroll
    for (int q = 0; q < 4; ++q)
      gload_lds16(Ab + eA[q] + kb, base + (q * 512 + tid) * 16);
  };
  auto STGB = [&](int t, int buf) {
    char* base = lds + buf * 57344 + 32768;
    uint32 kb = (uint32)t * 128;
#pragma unroll
    for (int q = 0; q < 3; ++q)
      gload_lds16(Bb + eB[q] + kb, base + (q * 512 + tid) * 16);
  };

  STGA(0, 0);
  STGB(0, 0);
  wait_vmcnt<0>();
  barrier_mem();

  for (int t = 0; t < nt; ++t) {
    const int buf = t & 1;
    const char* base = lds + buf * 57344;
    bf16x8 av[4], bv[6];

    // ---- phase 0 (physical ks = p) ----
#pragma unroll
    for (int n = 0; n < 6; ++n) bv[n] = *(const bf16x8*)(base + offB[0][n]);
#pragma unroll
    for (int m = 0; m < 4; ++m) av[m] = *(const bf16x8*)(base + offA[0][m]);
    if (t < nt - 1) {
      STGA(t + 1, buf ^ 1);
      STGB(t + 1, buf ^ 1);
    }
#pragma unroll
    for (int m = 0; m < 4; ++m)
#pragma unroll
      for (int n = 0; n < 6; ++n)
        acc[m][n] = __builtin_amdgcn_mfma_f32_16x16x32_bf16(av[m], bv[n], acc[m][n], 0, 0, 0);

    // ---- phase 1 (physical ks = p^1) ----
#pragma unroll
    for (int n = 0; n < 6; ++n) bv[n] = *(const bf16x8*)(base + offB[1][n]);
#pragma unroll
    for (int m = 0; m < 4; ++m) av[m] = *(const bf16x8*)(base + offA[1][m]);
#pragma unroll
    for (int m = 0; m < 4; ++m)
#pragma unroll
      for (int n = 0; n < 6; ++n)
        acc[m][n] = __builtin_amdgcn_mfma_f32_16x16x32_bf16(av[m], bv[n], acc[m][n], 0, 0, 0);

    if (t < nt - 1) {
      wait_vmcnt<0>();
      barrier_mem();
    }
  }

  // epilogue
#pragma unroll
  for (int n = 0; n < 6; ++n) {
    int col = bn0 + wn * 96 + n * 16 + lrow;
    if (col < N) {
      float bv2 = bias[col];
#pragma unroll
      for (int m = 0; m < 4; ++m) {
#pragma unroll
        for (int j = 0; j < 4; ++j) {
          int row = bm0 + wm * 64 + m * 16 + lj * 4 + j;
          C[(size_t)row * N + col] = acc[m][n][j] + bv2;
        }
      }
    }
  }
}

// ---------- stage 2 v3.1: chunk_fuse3 + wave-parity kf stagger (round-11 exact) ----------
__global__ __launch_bounds__(256, 2) void chunk_fuse3(
    const unsigned short* __restrict__ hb0, const unsigned short* __restrict__ hb1,
    const unsigned short* __restrict__ mWP, unsigned short* __restrict__ zb) {
  const int c = blockIdx.x, bt = blockIdx.y;
  __shared__ char wl[2][SLICE_B];   // 64 KB
  const int tid = threadIdx.x, wave = tid >> 6, lane = tid & 63;
  const int lrow = lane & 15, lj = lane >> 4;
  const int p = wave & 1;   // parity: kf iteration order (0,1,2) vs (2,1,0)

  bf16x8 bzero;
  bzero = (__bf16)0.0f;
  bf16x8 bone = bzero;
  bone[0] = (__bf16)1.0f;

  // h fragments -> registers in PERMUTED kf order; k=80 column = 1.0 (bias trick)
  bf16x8 a0[2][3], a1[2][3];
#pragma unroll
  for (int m = 0; m < 2; ++m)
#pragma unroll
    for (int i = 0; i < 3; ++i) {
      int kf = p ? 2 - i : i;
      int col = kf * 32 + lj * 8;
      int row = bt * 128 + wave * 32 + m * 16 + lrow;
      bf16x8 v0, v1;
      if (col < CSIZE) {
        size_t base = (size_t)row * MM + c * CSIZE + col;
        v0 = *(const bf16x8*)(hb0 + base);
        v1 = *(const bf16x8*)(hb1 + base);
      } else if (col == CSIZE) {
        v0 = bone; v1 = bone;
      } else {
        v0 = bzero; v1 = bzero;
      }
      a0[m][i] = v0;
      a1[m][i] = v1;
    }

  // swizzled W read offsets in the same permuted kf order
  int woff[3][5];
  const int key = (lrow >> 1) & 3;
#pragma unroll
  for (int i = 0; i < 3; ++i) {
    int kf = p ? 2 - i : i;
#pragma unroll
    for (int n = 0; n < 5; ++n) {
      int t = n * 16 + lrow;
      woff[i][n] = kf * (SL_KF * 2) + (t * 4 + (lj ^ key)) * 16;
    }
  }

  const char* wsrc = (const char*)(mWP) + (size_t)(c * RANK) * SLICE_B;
  auto STAGE = [&](int buf, int r) {
    const char* src = wsrc + (size_t)r * SLICE_B;
    char* dst = wl[buf];
#pragma unroll
    for (int k = 0; k < 8; ++k) {
      int i = k * 256 + tid;
      gload_lds16(src + (size_t)i * 16, dst + (size_t)i * 16);
    }
  };

  f32x4 zacc[2][5];
#pragma unroll
  for (int m = 0; m < 2; ++m)
#pragma unroll
    for (int n = 0; n < 5; ++n) zacc[m][n] = 0.f;
  f32x4 zero4 = 0.f;

  STAGE(0, 0);
  for (int r = 0; r < RANK; ++r) {
    int cur = r & 1;
    if (r < RANK - 1) {
      STAGE(cur ^ 1, r + 1);
      wait_vmcnt<8>();      // current slice landed; next 8 loads in flight
    } else {
      wait_vmcnt<0>();
    }
    __builtin_amdgcn_s_barrier();

    const char* wb = wl[cur];
    f32x4 y0[2][5], y1[2][5];
#pragma unroll
    for (int i = 0; i < 3; ++i) {
#pragma unroll
      for (int n = 0; n < 5; ++n) {
        bf16x8 b0 = *(const bf16x8*)(wb + woff[i][n]);
        bf16x8 b1 = *(const bf16x8*)(wb + SL_TEN * 2 + woff[i][n]);
        if (i == 0) {
#pragma unroll
          for (int m = 0; m < 2; ++m) {
            y0[m][n] = __builtin_amdgcn_mfma_f32_16x16x32_bf16(a0[m][0], b0, zero4, 0, 0, 0);
            y1[m][n] = __builtin_amdgcn_mfma_f32_16x16x32_bf16(a1[m][0], b1, zero4, 0, 0, 0);
          }
        } else {
#pragma unroll
          for (int m = 0; m < 2; ++m) {
            y0[m][n] = __builtin_amdgcn_mfma_f32_16x16x32_bf16(a0[m][i], b0, y0[m][n], 0, 0, 0);
            y1[m][n] = __builtin_amdgcn_mfma_f32_16x16x32_bf16(a1[m][i], b1, y1[m][n], 0, 0, 0);
          }
        }
      }
    }
    // bilinear accumulate (bias already inside y via k=80 column)
#pragma unroll
    for (int m = 0; m < 2; ++m)
#pragma unroll
      for (int n = 0; n < 5; ++n)
#pragma unroll
        for (int j = 0; j < 4; ++j)
          zacc[m][n][j] += y0[m][n][j] * y1[m][n][j];

    __builtin_amdgcn_s_barrier();  // all waves done reading wl[cur] before restage
  }

  // signed sqrt + per-row L2 norm over the 80 chunk cols, write bf16
#pragma unroll
  for (int m = 0; m < 2; ++m) {
    float g[5][4];
    float ssj[4] = {0.f, 0.f, 0.f, 0.f};
#pragma unroll
    for (int n = 0; n < 5; ++n)
#pragma unroll
      for (int j = 0; j < 4; ++j) {
        float v = zacc[m][n][j];
        float a = sqrtf(fabsf(v));
        float gv = v < 0.f ? -a : a;
        g[n][j] = gv;
        ssj[j] += gv * gv;
      }
#pragma unroll
    for (int j = 0; j < 4; ++j) {
      float s = ssj[j];
      s += __shfl_xor(s, 1);
      s += __shfl_xor(s, 2);
      s += __shfl_xor(s, 4);
      s += __shfl_xor(s, 8);
      float nrm = sqrtf(s);
      nrm = nrm > 1e-12f ? nrm : 1e-12f;
      ssj[j] = 1.f / nrm;
    }
#pragma unroll
    for (int n = 0; n < 5; ++n) {
      int scol = n * 16 + lrow;
#pragma unroll
      for (int j = 0; j < 4; ++j) {
        int row = bt * 128 + wave * 32 + m * 16 + lj * 4 + j;
        zb[(size_t)row * MM + c * CSIZE + scol] = f2bf(g[n][j] * ssj[j]);
      }
    }
  }
}

// ---------- workspace layout (bytes) ----------
#define OFF_XB0   ((size_t)0)
#define OFF_XB1   (OFF_XB0 + (size_t)BATCH * D0D1 * 2)
#define OFF_WB0   (OFF_XB1 + (size_t)BATCH * D0D1 * 2)
#define OFF_WB1   (OFF_WB0 + (size_t)MM * D0D1 * 2)
#define OFF_WOUTB (OFF_WB1 + (size_t)MM * D0D1 * 2)
#define OFF_HB0   (OFF_WOUTB + (size_t)NOUT * MM * 2)
#define OFF_HB1   (OFF_HB0 + (size_t)BATCH * MM * 2)
#define OFF_ZB    (OFF_HB1 + (size_t)BATCH * MM * 2)
#define WS_NEED   (OFF_ZB + (size_t)BATCH * MM * 2)
#define OFF_MWP   OFF_XB0   // mWP (9.8MB) aliases xb0 (16.8MB), packed after gemm_dual

extern "C" void kernel_launch(void* const* d_in, const int* in_sizes, int n_in,
                              void* d_out, int out_size, void* d_ws, size_t ws_size,
                              hipStream_t stream) {
  const float* x0   = (const float*)d_in[0];
  const float* x1   = (const float*)d_in[1];
  const float* W0   = (const float*)d_in[2];
  const float* b0   = (const float*)d_in[3];
  const float* W1   = (const float*)d_in[4];
  const float* b1   = (const float*)d_in[5];
  const float* mW0  = (const float*)d_in[6];
  const float* mb0  = (const float*)d_in[7];
  const float* mW1  = (const float*)d_in[8];
  const float* mb1  = (const float*)d_in[9];
  const float* Wout = (const float*)d_in[10];
  const float* bout = (const float*)d_in[11];

  if (ws_size < WS_NEED) return;

  char* ws = (char*)d_ws;
  unsigned short* xb0   = (unsigned short*)(ws + OFF_XB0);
  unsigned short* xb1   = (unsigned short*)(ws + OFF_XB1);
  unsigned short* Wb0   = (unsigned short*)(ws + OFF_WB0);
  unsigned short* Wb1   = (unsigned short*)(ws + OFF_WB1);
  unsigned short* Woutb = (unsigned short*)(ws + OFF_WOUTB);
  unsigned short* hb0   = (unsigned short*)(ws + OFF_HB0);
  unsigned short* hb1   = (unsigned short*)(ws + OFF_HB1);
  unsigned short* zb    = (unsigned short*)(ws + OFF_ZB);
  unsigned short* mWP   = (unsigned short*)(ws + OFF_MWP);

  // all 5 f32->bf16 casts in one launch
  hipLaunchKernelGGL(cast_all_k, dim3((CV_WO + 255) / 256), dim3(256), 0, stream,
                     x0, x1, W0, W1, Wout, xb0, xb1, Wb0, Wb1, Woutb);

  // stage 1: h0,h1 = x@W^T + b  -> bf16 [4096][1600]
  hipLaunchKernelGGL(gemm_dual_256, dim3(224), dim3(512), 0, stream,
                     xb0, Wb0, b0, hb0, xb1, Wb1, b1, hb1);

  // pack mW+mb (into xb0's space, now free): 300 slices x 2048 chunks
  hipLaunchKernelGGL(cast_mwp_k, dim3(8, RANK, NCHUNKS), dim3(256), 0, stream,
                     mW0, mb0, mW1, mb1, mWP);

  // stage 2: chunk MM + bilinear + signed sqrt + L2 norm -> zb bf16
  hipLaunchKernelGGL(chunk_fuse3, dim3(NCHUNKS, BATCH / 128), dim3(256), 0, stream,
                     hb0, hb1, mWP, zb);

  // stage 3: out = zn@Wout^T + bout -> f32 [4096][3000]
  hipLaunchKernelGGL(gemm_out_192, dim3(256), dim3(512), 0, stream,
                     zb, Woutb, bout, (float*)d_out);
}